// Round 10
// baseline (6314.700 us; speedup 1.0000x reference)
//
#include <hip/hip_runtime.h>

#define TINN 512
#define FF 64
#define HHD 512
#define TOUTN 64

using v8h = __attribute__((ext_vector_type(8))) _Float16;
using v4h = __attribute__((ext_vector_type(4))) _Float16;
using v4f = __attribute__((ext_vector_type(4))) float;
using u32x4 = __attribute__((ext_vector_type(4))) unsigned int;
using u64 = unsigned long long;

#define AGT __HIP_MEMORY_SCOPE_AGENT

// ---------------- LDS layout (bytes) ----------------
#define WOFF 0            // weights, MFMA fragment order (max 128KB)
#define BIAS_OFF 131072
#define WIH0_OFF 131328
#define PREV_OFF 131584
#define PART_OFF 131840
#define PROJW_OFF 132864
#define PROJB_OFF 134912
#define SMEM_TOTAL 134976

// ---------------- workspace layout ----------------
// Progress slots, then 6 h buffers, then fp16 swizzled x.
// h/x SWIZZLED LAYOUT: off(m,c) = (m>>4)*16384 + (c>>6)*2048 +
//   ((c>>5)&1)*1024 + ((c>>3)&3)*256 + (m&15)*16 + (c&7)*2
// -> a wave's A-fragment load is base + lane*16: 1KB fully coalesced.
#define WS_BAR 0
#define WS_HOFF 16384
#define HBYTES (256 * HHD * 2)
#define WS_XS (WS_HOFF + 6 * HBYTES)
#define XS_TBYTES 32768              // per-t: 16rt x 2ks x 1024 (kc=0 only)
#define WS_NEED (WS_XS + (size_t)TINN * XS_TBYTES)

static __device__ __forceinline__ float sigm(float x) { return 1.0f / (1.0f + __expf(-x)); }
static __device__ __forceinline__ float tanh_f(float x) { return 1.0f - 2.0f / (1.0f + __expf(2.0f * x)); }

// Cross-block h traffic: cache-bypass ops serviced at the LLC coherence
// point. No wbl2/inv fences emitted; read-only data stays cached.
static __device__ __forceinline__ v8h aload16(const _Float16* p) {
  union { u64 u[2]; v8h h; } c;
  const u64* q = (const u64*)p;
  c.u[0] = __hip_atomic_load(q, __ATOMIC_RELAXED, AGT);
  c.u[1] = __hip_atomic_load(q + 1, __ATOMIC_RELAXED, AGT);
  return c.h;
}
static __device__ __forceinline__ void astore8(_Float16* p, v4h v) {
  union { u64 u; v4h h; } c;
  c.h = v;
  __hip_atomic_store((u64*)p, c.u, __ATOMIC_RELAXED, AGT);
}
static __device__ __forceinline__ void astore8z(void* p) {
  __hip_atomic_store((u64*)p, 0ull, __ATOMIC_RELAXED, AGT);
}
static __device__ __forceinline__ void astore2(_Float16* p, float v) {
  __hip_atomic_store(p, (_Float16)v, __ATOMIC_RELAXED, AGT);
}

#if __has_builtin(__builtin_amdgcn_raw_ptr_buffer_load_b128) && \
    __has_builtin(__builtin_amdgcn_make_buffer_rsrc)
#define HAVE_BUFLOAD 1
using rsrc_t = __amdgpu_buffer_rsrc_t;
static __device__ __forceinline__ rsrc_t mkrsrc(const void* p) {
  return __builtin_amdgcn_make_buffer_rsrc((void*)p, (short)0, 0xFFFFFFFFu, 0x00020000);
}
static __device__ __forceinline__ v8h bload16(rsrc_t r, int byteOff) {
  union { u32x4 u; v8h h; } c;
  c.u = __builtin_amdgcn_raw_ptr_buffer_load_b128(r, byteOff, 0, 17);  // sc0|sc1
  return c.h;
}
#endif

static __device__ __forceinline__ void signalDone(unsigned* slots, int mySlot, unsigned val) {
  __builtin_amdgcn_s_waitcnt(0);
  __syncthreads();
  if (threadIdx.x == 0)
    __hip_atomic_store(&slots[(size_t)mySlot * 16], val, __ATOMIC_RELAXED, AGT);
}

// Poll one role's 32 slots (base = 0 or 32) until all >= tgt.
static __device__ __forceinline__ void waitRole(unsigned* slots, int base, int tgt) {
  if (tgt > 0) {
    if (threadIdx.x < 32) {
      while ((int)__hip_atomic_load(&slots[(size_t)(base + threadIdx.x) * 16],
                                    __ATOMIC_RELAXED, AGT) < tgt)
        __builtin_amdgcn_s_sleep(1);
    }
    __syncthreads();
#if __has_builtin(__builtin_amdgcn_sched_barrier)
    __builtin_amdgcn_sched_barrier(0);
#endif
  }
}

// Weight slice (64 gate-cols x K) fp32->fp16 into LDS, fragment order.
static __device__ __attribute__((noinline)) void loadWeights(
    int tid, int hc0, const float* W1, int ld1, int K1,
    const float* W2, int K) {
  extern __shared__ char smem[];
  int c = tid >> 2, sub = tid & 3;
  int nt = c >> 4, l = c & 15;
  int n = nt * HHD + hc0 + l;
  int Kq = K >> 2;
  for (int k = sub * Kq; k < (sub + 1) * Kq; ++k) {
    float v;
    if (k < K1) v = W1[(size_t)n * ld1 + k];
    else        v = W2[(size_t)n * HHD + (k - K1)];
    int kc = k >> 6, ks = (k >> 5) & 1, quad = (k >> 3) & 3, j = k & 7;
    int off = (((kc * 2 + ks) * 4 + nt) * 64 + quad * 16 + l) * 16 + j * 2;
    *(_Float16*)(smem + WOFF + off) = (_Float16)v;
  }
}

// 8 K-chunks of MFMA from swizzled src (h buffers), weight chunks WC0..WC0+7.
template <int WC0>
static __device__ __forceinline__ void mfma8(
    const _Float16* src, int rt, int lane, const char* wbLane, v4f* acc) {
#if HAVE_BUFLOAD
  rsrc_t rs = mkrsrc(src);
#endif
#pragma unroll
  for (int kc = 0; kc < 8; ++kc) {
    int off = rt * 16384 + kc * 2048 + lane * 16;
    v8h ak0, ak1;
#if HAVE_BUFLOAD
    ak0 = bload16(rs, off);
    ak1 = bload16(rs, off + 1024);
#else
    ak0 = aload16(src + off / 2);
    ak1 = aload16(src + (off + 1024) / 2);
#endif
    const char* bb = wbLane + (size_t)(WC0 + kc) * 8192;
#pragma unroll
    for (int ks = 0; ks < 2; ++ks) {
      v8h a = ks ? ak1 : ak0;
      acc[0] = __builtin_amdgcn_mfma_f32_16x16x32_f16(a, *(const v8h*)(bb + (ks * 4 + 0) * 1024), acc[0], 0, 0, 0);
      acc[1] = __builtin_amdgcn_mfma_f32_16x16x32_f16(a, *(const v8h*)(bb + (ks * 4 + 1) * 1024), acc[1], 0, 0, 0);
      acc[2] = __builtin_amdgcn_mfma_f32_16x16x32_f16(a, *(const v8h*)(bb + (ks * 4 + 2) * 1024), acc[2], 0, 0, 0);
      acc[3] = __builtin_amdgcn_mfma_f32_16x16x32_f16(a, *(const v8h*)(bb + (ks * 4 + 3) * 1024), acc[3], 0, 0, 0);
    }
  }
}

// x chunk (weight chunk 0): swizzled fp16 xs (cached) or raw fp32 fallback.
static __device__ __forceinline__ void xChunk(
    const char* xsT, const float* xstep, int m0, int tid,
    const char* wbLane, v4f* acc) {
  int lane = tid & 63, wave = tid >> 6;
  int l15 = lane & 15, quad = lane >> 4;
  v8h ak0, ak1;
  if (xsT != nullptr) {
    int rt = (m0 >> 4) + wave;
    const char* xb = xsT + rt * 2048 + lane * 16;
    ak0 = *(const v8h*)(xb);
    ak1 = *(const v8h*)(xb + 1024);
  } else {
    int ra = m0 + wave * 16 + l15;
    const float* xr = xstep + (size_t)ra * (TINN * FF) + quad * 8;
    v4f f00 = *(const v4f*)(xr);
    v4f f01 = *(const v4f*)(xr + 4);
    v4f f10 = *(const v4f*)(xr + 32);
    v4f f11 = *(const v4f*)(xr + 36);
#pragma unroll
    for (int e = 0; e < 4; ++e) {
      ak0[e] = (_Float16)f00[e]; ak0[4 + e] = (_Float16)f01[e];
      ak1[e] = (_Float16)f10[e]; ak1[4 + e] = (_Float16)f11[e];
    }
  }
#pragma unroll
  for (int ks = 0; ks < 2; ++ks) {
    v8h a = ks ? ak1 : ak0;
    acc[0] = __builtin_amdgcn_mfma_f32_16x16x32_f16(a, *(const v8h*)(wbLane + (ks * 4 + 0) * 1024), acc[0], 0, 0, 0);
    acc[1] = __builtin_amdgcn_mfma_f32_16x16x32_f16(a, *(const v8h*)(wbLane + (ks * 4 + 1) * 1024), acc[1], 0, 0, 0);
    acc[2] = __builtin_amdgcn_mfma_f32_16x16x32_f16(a, *(const v8h*)(wbLane + (ks * 4 + 2) * 1024), acc[2], 0, 0, 0);
    acc[3] = __builtin_amdgcn_mfma_f32_16x16x32_f16(a, *(const v8h*)(wbLane + (ks * 4 + 3) * 1024), acc[3], 0, 0, 0);
  }
}

// In-register epilogue: acc0..3 = gates i,f,g,o for cell
// (row = wave*16 + quad*4 + r, col = hc0 + l15). No LDS roundtrip.
static __device__ __forceinline__ void epilogue(
    int tid, int m0, int hc0, int rank1, _Float16* hout, float* creg, v4f* acc) {
  extern __shared__ char smem[];
  int lane = tid & 63, wave = tid >> 6;
  int l15 = lane & 15, quad = lane >> 4;
  float* bias = (float*)(smem + BIAS_OFF);
  float bi = bias[l15], bf = bias[16 + l15], bg = bias[32 + l15], bo = bias[48 + l15];
  float wi = 0.f, wf = 0.f, wg = 0.f, wo = 0.f;
  if (rank1) {
    float* wih0 = (float*)(smem + WIH0_OFF);
    wi = wih0[l15]; wf = wih0[16 + l15]; wg = wih0[32 + l15]; wo = wih0[48 + l15];
  }
  float* prevl = (float*)(smem + PREV_OFF);
  int c = hc0 + l15;
  int colOff = (c >> 6) * 2048 + ((c >> 5) & 1) * 1024 + ((c >> 3) & 3) * 256 + (c & 7) * 2;
#pragma unroll
  for (int r = 0; r < 4; ++r) {
    int mloc = wave * 16 + quad * 4 + r;
    float gi = acc[0][r] + bi, gf = acc[1][r] + bf;
    float gg = acc[2][r] + bg, go = acc[3][r] + bo;
    if (rank1) {
      float pv = prevl[mloc];
      gi += pv * wi; gf += pv * wf; gg += pv * wg; go += pv * wo;
    }
    float cc = sigm(gf) * creg[r] + sigm(gi) * tanh_f(gg);
    float h = sigm(go) * tanh_f(cc);
    creg[r] = cc;
    int m = m0 + mloc;
    int off = (m >> 4) * 16384 + colOff + (m & 15) * 16;
    astore2((_Float16*)((char*)hout + off), h);
  }
}

// ---- step functions (noinline: compile-crash hygiene) ----

// enc0 step p: wait role0 -> x + h chunks -> (late) reuse guard -> epilogue.
static __device__ __attribute__((noinline)) void stepEnc0(
    int tid, int m0, int hc0, unsigned* slots, int mySlot, int p,
    const char* xsT, const float* xstep,
    const _Float16* h0prev, _Float16* h0out, float* creg) {
  extern __shared__ char smem[];
  int lane = tid & 63, wave = tid >> 6;
  v4f acc[4];
  acc[0] = v4f{0.f, 0.f, 0.f, 0.f}; acc[1] = acc[0]; acc[2] = acc[0]; acc[3] = acc[0];
  const char* wbLane = smem + WOFF + (size_t)lane * 16;
  waitRole(slots, 0, p + 1);          // h0(p-1) ready (and init for xs)
  xChunk(xsT, xstep, m0, tid, wbLane, acc);
  mfma8<1>(h0prev, (m0 >> 4) + wave, lane, wbLane, acc);
  waitRole(slots, 32, p - 2);         // write-reuse guard (usually free)
  epilogue(tid, m0, hc0, 0, h0out, creg, acc);
  signalDone(slots, mySlot, p + 2);
}

// L1-style step (enc1 & dec1): role1 wait -> h1 half -> role0 wait -> h0 half.
static __device__ __attribute__((noinline)) void stepL1(
    int tid, int m0, int hc0, unsigned* slots, int mySlot, int tR1, int tR0,
    const _Float16* h0src, const _Float16* h1prev, _Float16* h1out, float* creg) {
  extern __shared__ char smem[];
  int lane = tid & 63, wave = tid >> 6;
  v4f acc[4];
  acc[0] = v4f{0.f, 0.f, 0.f, 0.f}; acc[1] = acc[0]; acc[2] = acc[0]; acc[3] = acc[0];
  const char* wbLane = smem + WOFF + (size_t)lane * 16;
  int rt = (m0 >> 4) + wave;
  waitRole(slots, 32, tR1);           // h1(prev) ready + reuse guard
  mfma8<8>(h1prev, rt, lane, wbLane, acc);
  waitRole(slots, 0, tR0);            // h0(cur) ready — hidden behind h1 half
  mfma8<0>(h0src, rt, lane, wbLane, acc);
  epilogue(tid, m0, hc0, 0, h1out, creg, acc);
  signalDone(slots, mySlot, tR0);
}

// dec0 gemm step (after proj): wait role0 -> h chunks -> rank1 epilogue.
static __device__ __attribute__((noinline)) void stepDec0(
    int tid, int m0, int hc0, unsigned* slots, int mySlot, int u,
    const _Float16* h0prev, _Float16* h0out, float* creg) {
  extern __shared__ char smem[];
  int lane = tid & 63, wave = tid >> 6;
  v4f acc[4];
  acc[0] = v4f{0.f, 0.f, 0.f, 0.f}; acc[1] = acc[0]; acc[2] = acc[0]; acc[3] = acc[0];
  const char* wbLane = smem + WOFF + (size_t)lane * 16;
  waitRole(slots, 0, u + 1);          // h0(t-1) ready (own role)
  mfma8<0>(h0prev, (m0 >> 4) + wave, lane, wbLane, acc);
  epilogue(tid, m0, hc0, 1, h0out, creg, acc);
  signalDone(slots, mySlot, u + 2);
}

__global__ void __launch_bounds__(256, 1)
seq2seq_kernel(const float* x,
               const float* e0wi, const float* e0wh, const float* e0bi, const float* e0bh,
               const float* e1wi, const float* e1wh, const float* e1bi, const float* e1bh,
               const float* d0wi, const float* d0wh, const float* d0bi, const float* d0bh,
               const float* d1wi, const float* d1wh, const float* d1bi, const float* d1bh,
               const float* pw, const float* pb,
               float* out, char* ws, int useXs) {
  extern __shared__ char smem[];
  int tid = threadIdx.x, bid = blockIdx.x;
  int group = bid >> 6;
  int r = bid & 63;
  bool isL1 = (r >= 32);
  int hcTile = r & 31;
  int hc0 = hcTile * 16;
  int m0 = group * 64;
  unsigned* slots = (unsigned*)(ws + WS_BAR) + (size_t)group * 1024;
  int mySlot = isL1 ? 32 + hcTile : hcTile;
  char* xs = useXs ? (ws + WS_XS) : nullptr;

  _Float16* h0b[4]; _Float16* h1b[2];
  h0b[0] = (_Float16*)(ws + WS_HOFF);
  h0b[1] = (_Float16*)(ws + WS_HOFF + 1 * HBYTES);
  h0b[2] = (_Float16*)(ws + WS_HOFF + 2 * HBYTES);
  h0b[3] = (_Float16*)(ws + WS_HOFF + 3 * HBYTES);
  h1b[0] = (_Float16*)(ws + WS_HOFF + 4 * HBYTES);
  h1b[1] = (_Float16*)(ws + WS_HOFF + 5 * HBYTES);

  float creg[4];
  creg[0] = 0.f; creg[1] = 0.f; creg[2] = 0.f; creg[3] = 0.f;

  // zero the "step -1" buffers (h0[3], h1[1]) group slice
  {
    int t16 = r * 256 + tid;
    char* base = (t16 < 8192) ? (char*)h0b[3] : (char*)h1b[1];
    int idx = t16 & 8191;
    astore8z(base + (size_t)m0 * HHD * 2 + (size_t)idx * 8);
  }

  // one-time x -> xs transpose (fp32 -> fp16 swizzled), block r does t=r+64k
  if (xs) {
    int m = m0 + (tid & 63);
    int cb = (tid >> 6) * 16;
    int rt = m >> 4, l15m = m & 15;
    for (int k = 0; k < 8; ++k) {
      int t = r + k * 64;
      const float* xp = x + (size_t)m * (TINN * FF) + (size_t)t * FF + cb;
      v4f f0 = *(const v4f*)(xp);
      v4f f1 = *(const v4f*)(xp + 4);
      v4f f2 = *(const v4f*)(xp + 8);
      v4f f3 = *(const v4f*)(xp + 12);
      v4h h0_, h1_, h2_, h3_;
#pragma unroll
      for (int e = 0; e < 4; ++e) {
        h0_[e] = (_Float16)f0[e]; h1_[e] = (_Float16)f1[e];
        h2_[e] = (_Float16)f2[e]; h3_[e] = (_Float16)f3[e];
      }
      char* xt = xs + (size_t)t * XS_TBYTES;
      v4h hs[4] = {h0_, h1_, h2_, h3_};
#pragma unroll
      for (int s = 0; s < 4; ++s) {
        int c0 = cb + 4 * s;
        int off = (rt * 2 + ((c0 >> 5) & 1)) * 1024 +
                  ((c0 >> 3) & 3) * 256 + l15m * 16 + (c0 & 7) * 2;
        astore8((_Float16*)(xt + off), hs[s]);
      }
    }
  }

  if (!isL1) {
    loadWeights(tid, hc0, e0wi, 64, 64, e0wh, 576);
    if (tid < 64) {
      int n = (tid >> 4) * HHD + hc0 + (tid & 15);
      ((float*)(smem + BIAS_OFF))[tid] = e0bi[n] + e0bh[n];
    }
  } else {
    loadWeights(tid, hc0, e1wi, 512, 512, e1wh, 1024);
    if (tid < 64) {
      int n = (tid >> 4) * HHD + hc0 + (tid & 15);
      ((float*)(smem + BIAS_OFF))[tid] = e1bi[n] + e1bh[n];
    }
  }
  signalDone(slots, mySlot, 1);

  if (!isL1) {
    // ---------------- encoder layer 0 ----------------
    for (int p = 0; p < TINN; ++p)
      stepEnc0(tid, m0, hc0, slots, mySlot, p,
               xs ? xs + (size_t)p * XS_TBYTES : nullptr,
               xs ? nullptr : x + (size_t)p * FF,
               h0b[(p + 3) & 3], h0b[p & 3], creg);
    // ---------------- decoder layer 0 ----------------
    loadWeights(tid, hc0, d0wh, 512, 512, nullptr, 512);
    if (tid < 64) {
      int n = (tid >> 4) * HHD + hc0 + (tid & 15);
      ((float*)(smem + BIAS_OFF))[tid] = d0bi[n] + d0bh[n];
      ((float*)(smem + WIH0_OFF))[tid] = d0wi[n];
    }
    for (int k = tid; k < 512; k += 256) ((float*)(smem + PROJW_OFF))[k] = pw[k];
    if (tid == 0) ((float*)(smem + PROJB_OFF))[0] = pb[0];
    for (int t = 0; t <= TOUTN; ++t) {
      int u = TINN + t;
      waitRole(slots, 32, u + 1);     // h1(t-1) ready
      float* prevl = (float*)(smem + PREV_OFF);
      if (t == 0) {
        if (tid < 64)
          prevl[tid] = x[(size_t)(m0 + tid) * (TINN * FF) + 511 * 64 + 63];
      } else {
        float* part = (float*)(smem + PART_OFF);
        float* pjw = (float*)(smem + PROJW_OFF);
        const _Float16* h1base = h1b[(u + 1) & 1];
        int m = m0 + (tid >> 2);
        int rt = m >> 4, l15m = m & 15;
        int kc0 = (tid & 3) * 2;
        float s = 0.f;
#pragma unroll
        for (int kc = kc0; kc < kc0 + 2; ++kc)
#pragma unroll
          for (int ks = 0; ks < 2; ++ks)
#pragma unroll
            for (int q = 0; q < 4; ++q) {
              int off = (rt * 8 + kc) * 2048 + ks * 1024 + q * 256 + l15m * 16;
              v8h hv = aload16(h1base + off / 2);
              const float* w = pjw + kc * 64 + ks * 32 + q * 8;
#pragma unroll
              for (int e = 0; e < 8; ++e) s += (float)hv[e] * w[e];
            }
        part[tid] = s;
        __syncthreads();
        if (tid < 64) {
          float p4 = part[tid * 4] + part[tid * 4 + 1] + part[tid * 4 + 2] +
                     part[tid * 4 + 3] + ((float*)(smem + PROJB_OFF))[0];
          prevl[tid] = p4;
          if (hcTile == 0) out[(size_t)(m0 + tid) * TOUTN + (t - 1)] = p4;
        }
      }
      __syncthreads();
      if (t < TOUTN)
        stepDec0(tid, m0, hc0, slots, mySlot, u, h0b[(u + 3) & 3], h0b[u & 3], creg);
    }
  } else {
    // ---------------- encoder layer 1 ----------------
    for (int s = 0; s < TINN; ++s)
      stepL1(tid, m0, hc0, slots, mySlot, s + 1, s + 2,
             h0b[s & 3], h1b[(s + 1) & 1], h1b[s & 1], creg);
    // ---------------- decoder layer 1 ----------------
    loadWeights(tid, hc0, d1wi, 512, 512, d1wh, 1024);
    if (tid < 64) {
      int n = (tid >> 4) * HHD + hc0 + (tid & 15);
      ((float*)(smem + BIAS_OFF))[tid] = d1bi[n] + d1bh[n];
    }
    for (int t = 0; t < TOUTN; ++t) {
      int u = TINN + t;
      stepL1(tid, m0, hc0, slots, mySlot, u + 1, u + 2,
             h0b[u & 3], h1b[(u + 1) & 1], h1b[u & 1], creg);
    }
  }
}

extern "C" void kernel_launch(void* const* d_in, const int* in_sizes, int n_in,
                              void* d_out, int out_size, void* d_ws, size_t ws_size,
                              hipStream_t stream) {
  const float* x = (const float*)d_in[0];
  const float* e0wi = (const float*)d_in[2];
  const float* e0wh = (const float*)d_in[3];
  const float* e0bi = (const float*)d_in[4];
  const float* e0bh = (const float*)d_in[5];
  const float* e1wi = (const float*)d_in[6];
  const float* e1wh = (const float*)d_in[7];
  const float* e1bi = (const float*)d_in[8];
  const float* e1bh = (const float*)d_in[9];
  const float* d0wi = (const float*)d_in[10];
  const float* d0wh = (const float*)d_in[11];
  const float* d0bi = (const float*)d_in[12];
  const float* d0bh = (const float*)d_in[13];
  const float* d1wi = (const float*)d_in[14];
  const float* d1wh = (const float*)d_in[15];
  const float* d1bi = (const float*)d_in[16];
  const float* d1bh = (const float*)d_in[17];
  const float* pw = (const float*)d_in[18];
  const float* pb = (const float*)d_in[19];

  int useXs = (ws_size >= WS_NEED) ? 1 : 0;
  (void)hipFuncSetAttribute((const void*)seq2seq_kernel,
                            hipFuncAttributeMaxDynamicSharedMemorySize, SMEM_TOTAL);
  (void)hipMemsetAsync(d_ws, 0, 16384, stream);  // progress slots
  seq2seq_kernel<<<dim3(256), dim3(256), SMEM_TOTAL, stream>>>(
      x, e0wi, e0wh, e0bi, e0bh, e1wi, e1wh, e1bi, e1bh,
      d0wi, d0wh, d0bi, d0bh, d1wi, d1wh, d1bi, d1bh,
      pw, pb, (float*)d_out, (char*)d_ws, useXs);
}

// Round 11
// 4551.474 us; speedup vs baseline: 1.3874x; 1.3874x over previous
//
#include <hip/hip_runtime.h>

#define TINN 512
#define FF 64
#define HHD 512
#define TOUTN 64

using v8h = __attribute__((ext_vector_type(8))) _Float16;
using v4h = __attribute__((ext_vector_type(4))) _Float16;
using v4f = __attribute__((ext_vector_type(4))) float;
using u32x4 = __attribute__((ext_vector_type(4))) unsigned int;
using u64 = unsigned long long;

#define AGT __HIP_MEMORY_SCOPE_AGENT

// ---------------- LDS layout (bytes) ----------------
#define WOFF 0            // weights, MFMA fragment order (max 128KB)
#define BIAS_OFF 131072
#define WIH0_OFF 131328
#define PREV_OFF 131584
#define PART_OFF 131840
#define PROJW_OFF 132864
#define PROJB_OFF 134912
#define TRANS_OFF 134976  // 4 waves x 512B h-transpose scratch
#define SMEM_TOTAL 137024

// ---------------- workspace layout ----------------
// Progress slots, then 6 h buffers, then fp16 swizzled x.
// h/x SWIZZLED LAYOUT: off(m,c) = (m>>4)*16384 + (c>>6)*2048 +
//   ((c>>5)&1)*1024 + ((c>>3)&3)*256 + (m&15)*16 + (c&7)*2
// -> a wave's A-fragment load is base + lane*16: 1KB fully coalesced.
#define WS_BAR 0
#define WS_HOFF 16384
#define HBYTES (256 * HHD * 2)
#define WS_XS (WS_HOFF + 6 * HBYTES)
#define XS_TBYTES 32768              // per-t: 16rt x 2ks x 1024 (kc=0 only)
#define WS_NEED (WS_XS + (size_t)TINN * XS_TBYTES)

static __device__ __forceinline__ float sigm(float x) { return 1.0f / (1.0f + __expf(-x)); }
static __device__ __forceinline__ float tanh_f(float x) { return 1.0f - 2.0f / (1.0f + __expf(2.0f * x)); }

// Cross-block h traffic: cache-bypass ops serviced at the LLC coherence
// point. No wbl2/inv fences emitted; read-only data stays cached.
static __device__ __forceinline__ v8h aload16(const _Float16* p) {
  union { u64 u[2]; v8h h; } c;
  const u64* q = (const u64*)p;
  c.u[0] = __hip_atomic_load(q, __ATOMIC_RELAXED, AGT);
  c.u[1] = __hip_atomic_load(q + 1, __ATOMIC_RELAXED, AGT);
  return c.h;
}
static __device__ __forceinline__ void astore8(_Float16* p, v4h v) {
  union { u64 u; v4h h; } c;
  c.h = v;
  __hip_atomic_store((u64*)p, c.u, __ATOMIC_RELAXED, AGT);
}
static __device__ __forceinline__ void astore8z(void* p) {
  __hip_atomic_store((u64*)p, 0ull, __ATOMIC_RELAXED, AGT);
}

#if __has_builtin(__builtin_amdgcn_raw_ptr_buffer_load_b128) && \
    __has_builtin(__builtin_amdgcn_make_buffer_rsrc)
#define HAVE_BUFLOAD 1
using rsrc_t = __amdgpu_buffer_rsrc_t;
static __device__ __forceinline__ rsrc_t mkrsrc(const void* p) {
  return __builtin_amdgcn_make_buffer_rsrc((void*)p, (short)0, 0xFFFFFFFFu, 0x00020000);
}
static __device__ __forceinline__ v8h bload16(rsrc_t r, int byteOff) {
  union { u32x4 u; v8h h; } c;
  c.u = __builtin_amdgcn_raw_ptr_buffer_load_b128(r, byteOff, 0, 17);  // sc0|sc1
  return c.h;
}
#endif

static __device__ __forceinline__ void signalDone(unsigned* slots, int mySlot, unsigned val) {
  __builtin_amdgcn_s_waitcnt(0);
  __syncthreads();
  if (threadIdx.x == 0)
    __hip_atomic_store(&slots[(size_t)mySlot * 16], val, __ATOMIC_RELAXED, AGT);
}

// Poll one role's 32 slots (base = 0 or 32) until all >= tgt.
static __device__ __forceinline__ void waitRole(unsigned* slots, int base, int tgt) {
  if (tgt > 0) {
    if (threadIdx.x < 32) {
      while ((int)__hip_atomic_load(&slots[(size_t)(base + threadIdx.x) * 16],
                                    __ATOMIC_RELAXED, AGT) < tgt)
        __builtin_amdgcn_s_sleep(1);
    }
    __syncthreads();
#if __has_builtin(__builtin_amdgcn_sched_barrier)
    __builtin_amdgcn_sched_barrier(0);
#endif
  }
}

// Weight slice (64 gate-cols x K) fp32->fp16 into LDS, fragment order.
static __device__ __attribute__((noinline)) void loadWeights(
    int tid, int hc0, const float* W1, int ld1, int K1,
    const float* W2, int K) {
  extern __shared__ char smem[];
  int c = tid >> 2, sub = tid & 3;
  int nt = c >> 4, l = c & 15;
  int n = nt * HHD + hc0 + l;
  int Kq = K >> 2;
  for (int k = sub * Kq; k < (sub + 1) * Kq; ++k) {
    float v;
    if (k < K1) v = W1[(size_t)n * ld1 + k];
    else        v = W2[(size_t)n * HHD + (k - K1)];
    int kc = k >> 6, ks = (k >> 5) & 1, quad = (k >> 3) & 3, j = k & 7;
    int off = (((kc * 2 + ks) * 4 + nt) * 64 + quad * 16 + l) * 16 + j * 2;
    *(_Float16*)(smem + WOFF + off) = (_Float16)v;
  }
}

// 8 K-chunks of MFMA from swizzled src (h buffers), weight chunks WC0..WC0+7.
template <int WC0>
static __device__ __forceinline__ void mfma8(
    const _Float16* src, int rt, int lane, const char* wbLane, v4f* acc) {
#if HAVE_BUFLOAD
  rsrc_t rs = mkrsrc(src);
#endif
#pragma unroll
  for (int kc = 0; kc < 8; ++kc) {
    int off = rt * 16384 + kc * 2048 + lane * 16;
    v8h ak0, ak1;
#if HAVE_BUFLOAD
    ak0 = bload16(rs, off);
    ak1 = bload16(rs, off + 1024);
#else
    ak0 = aload16(src + off / 2);
    ak1 = aload16(src + (off + 1024) / 2);
#endif
    const char* bb = wbLane + (size_t)(WC0 + kc) * 8192;
#pragma unroll
    for (int ks = 0; ks < 2; ++ks) {
      v8h a = ks ? ak1 : ak0;
      acc[0] = __builtin_amdgcn_mfma_f32_16x16x32_f16(a, *(const v8h*)(bb + (ks * 4 + 0) * 1024), acc[0], 0, 0, 0);
      acc[1] = __builtin_amdgcn_mfma_f32_16x16x32_f16(a, *(const v8h*)(bb + (ks * 4 + 1) * 1024), acc[1], 0, 0, 0);
      acc[2] = __builtin_amdgcn_mfma_f32_16x16x32_f16(a, *(const v8h*)(bb + (ks * 4 + 2) * 1024), acc[2], 0, 0, 0);
      acc[3] = __builtin_amdgcn_mfma_f32_16x16x32_f16(a, *(const v8h*)(bb + (ks * 4 + 3) * 1024), acc[3], 0, 0, 0);
    }
  }
}

// x chunk (weight chunk 0): swizzled fp16 xs (cached) or raw fp32 fallback.
static __device__ __forceinline__ void xChunk(
    const char* xsT, const float* xstep, int m0, int tid,
    const char* wbLane, v4f* acc) {
  int lane = tid & 63, wave = tid >> 6;
  int l15 = lane & 15, quad = lane >> 4;
  v8h ak0, ak1;
  if (xsT != nullptr) {
    int rt = (m0 >> 4) + wave;
    const char* xb = xsT + rt * 2048 + lane * 16;
    ak0 = *(const v8h*)(xb);
    ak1 = *(const v8h*)(xb + 1024);
  } else {
    int ra = m0 + wave * 16 + l15;
    const float* xr = xstep + (size_t)ra * (TINN * FF) + quad * 8;
    v4f f00 = *(const v4f*)(xr);
    v4f f01 = *(const v4f*)(xr + 4);
    v4f f10 = *(const v4f*)(xr + 32);
    v4f f11 = *(const v4f*)(xr + 36);
#pragma unroll
    for (int e = 0; e < 4; ++e) {
      ak0[e] = (_Float16)f00[e]; ak0[4 + e] = (_Float16)f01[e];
      ak1[e] = (_Float16)f10[e]; ak1[4 + e] = (_Float16)f11[e];
    }
  }
#pragma unroll
  for (int ks = 0; ks < 2; ++ks) {
    v8h a = ks ? ak1 : ak0;
    acc[0] = __builtin_amdgcn_mfma_f32_16x16x32_f16(a, *(const v8h*)(wbLane + (ks * 4 + 0) * 1024), acc[0], 0, 0, 0);
    acc[1] = __builtin_amdgcn_mfma_f32_16x16x32_f16(a, *(const v8h*)(wbLane + (ks * 4 + 1) * 1024), acc[1], 0, 0, 0);
    acc[2] = __builtin_amdgcn_mfma_f32_16x16x32_f16(a, *(const v8h*)(wbLane + (ks * 4 + 2) * 1024), acc[2], 0, 0, 0);
    acc[3] = __builtin_amdgcn_mfma_f32_16x16x32_f16(a, *(const v8h*)(wbLane + (ks * 4 + 3) * 1024), acc[3], 0, 0, 0);
  }
}

// In-register gate math + per-wave LDS mini-transpose for a coalesced 8B
// h write. Gate domain: acc0..3[r] = gates i,f,g,o for cell
// (mloc = wave*16 + quad*4 + r, c = hc0 + l15). Write domain: lane holds
// (mloc = wave*16 + (lane&15), c = hc0 + (lane>>4)*4 .. +3) -> one astore8.
// Wave-local LDS is processed in order: no barrier needed.
static __device__ __forceinline__ void epilogue(
    int tid, int m0, int hc0, int rank1, _Float16* hout, float* creg, v4f* acc) {
  extern __shared__ char smem[];
  int lane = tid & 63, wave = tid >> 6;
  int l15 = lane & 15, quad = lane >> 4;
  float* bias = (float*)(smem + BIAS_OFF);
  float bi = bias[l15], bf = bias[16 + l15], bg = bias[32 + l15], bo = bias[48 + l15];
  float wi = 0.f, wf = 0.f, wg = 0.f, wo = 0.f;
  if (rank1) {
    float* wih0 = (float*)(smem + WIH0_OFF);
    wi = wih0[l15]; wf = wih0[16 + l15]; wg = wih0[32 + l15]; wo = wih0[48 + l15];
  }
  float* prevl = (float*)(smem + PREV_OFF);
  _Float16* tb = (_Float16*)(smem + TRANS_OFF + (size_t)wave * 512);
#pragma unroll
  for (int r = 0; r < 4; ++r) {
    int mloc = wave * 16 + quad * 4 + r;
    float gi = acc[0][r] + bi, gf = acc[1][r] + bf;
    float gg = acc[2][r] + bg, go = acc[3][r] + bo;
    if (rank1) {
      float pv = prevl[mloc];
      gi += pv * wi; gf += pv * wf; gg += pv * wg; go += pv * wo;
    }
    float cc = sigm(gf) * creg[r] + sigm(gi) * tanh_f(gg);
    float h = sigm(go) * tanh_f(cc);
    creg[r] = cc;
    tb[(quad * 4 + r) * 16 + l15] = (_Float16)h;   // m-fast deposit
  }
  // c-fast pickup: one 8B read + one 8B coalesced bypass store
  {
    int mloc = lane & 15, cg = lane >> 4;
    v4h hv = *(const v4h*)(tb + mloc * 16 + cg * 4);
    int m = m0 + wave * 16 + mloc;
    int c0 = hc0 + cg * 4;
    int off = (m >> 4) * 16384 + (c0 >> 6) * 2048 + ((c0 >> 5) & 1) * 1024 +
              ((c0 >> 3) & 3) * 256 + (m & 15) * 16 + (c0 & 7) * 2;
    astore8((_Float16*)((char*)hout + off), hv);
  }
}

// ---- step functions (noinline: compile-crash hygiene) ----

// enc0 step p: wait role0 -> x + h chunks -> (late) reuse guard -> epilogue.
static __device__ __attribute__((noinline)) void stepEnc0(
    int tid, int m0, int hc0, unsigned* slots, int mySlot, int p,
    const char* xsT, const float* xstep,
    const _Float16* h0prev, _Float16* h0out, float* creg) {
  extern __shared__ char smem[];
  int lane = tid & 63, wave = tid >> 6;
  v4f acc[4];
  acc[0] = v4f{0.f, 0.f, 0.f, 0.f}; acc[1] = acc[0]; acc[2] = acc[0]; acc[3] = acc[0];
  const char* wbLane = smem + WOFF + (size_t)lane * 16;
  waitRole(slots, 0, p + 1);          // h0(p-1) ready (and init for xs)
  xChunk(xsT, xstep, m0, tid, wbLane, acc);
  mfma8<1>(h0prev, (m0 >> 4) + wave, lane, wbLane, acc);
  waitRole(slots, 32, p - 2);         // write-reuse guard (usually free)
  epilogue(tid, m0, hc0, 0, h0out, creg, acc);
  signalDone(slots, mySlot, p + 2);
}

// L1-style step (enc1 & dec1): role1 wait -> h1 half -> role0 wait -> h0 half.
static __device__ __attribute__((noinline)) void stepL1(
    int tid, int m0, int hc0, unsigned* slots, int mySlot, int tR1, int tR0,
    const _Float16* h0src, const _Float16* h1prev, _Float16* h1out, float* creg) {
  extern __shared__ char smem[];
  int lane = tid & 63, wave = tid >> 6;
  v4f acc[4];
  acc[0] = v4f{0.f, 0.f, 0.f, 0.f}; acc[1] = acc[0]; acc[2] = acc[0]; acc[3] = acc[0];
  const char* wbLane = smem + WOFF + (size_t)lane * 16;
  int rt = (m0 >> 4) + wave;
  waitRole(slots, 32, tR1);           // h1(prev) ready + reuse guard
  mfma8<8>(h1prev, rt, lane, wbLane, acc);
  waitRole(slots, 0, tR0);            // h0(cur) ready — hidden behind h1 half
  mfma8<0>(h0src, rt, lane, wbLane, acc);
  epilogue(tid, m0, hc0, 0, h1out, creg, acc);
  signalDone(slots, mySlot, tR0);
}

// dec0 gemm step (after proj): wait role0 -> h chunks -> rank1 epilogue.
static __device__ __attribute__((noinline)) void stepDec0(
    int tid, int m0, int hc0, unsigned* slots, int mySlot, int u,
    const _Float16* h0prev, _Float16* h0out, float* creg) {
  extern __shared__ char smem[];
  int lane = tid & 63, wave = tid >> 6;
  v4f acc[4];
  acc[0] = v4f{0.f, 0.f, 0.f, 0.f}; acc[1] = acc[0]; acc[2] = acc[0]; acc[3] = acc[0];
  const char* wbLane = smem + WOFF + (size_t)lane * 16;
  waitRole(slots, 0, u + 1);          // h0(t-1) ready (own role)
  mfma8<0>(h0prev, (m0 >> 4) + wave, lane, wbLane, acc);
  epilogue(tid, m0, hc0, 1, h0out, creg, acc);
  signalDone(slots, mySlot, u + 2);
}

__global__ void __launch_bounds__(256, 1)
seq2seq_kernel(const float* x,
               const float* e0wi, const float* e0wh, const float* e0bi, const float* e0bh,
               const float* e1wi, const float* e1wh, const float* e1bi, const float* e1bh,
               const float* d0wi, const float* d0wh, const float* d0bi, const float* d0bh,
               const float* d1wi, const float* d1wh, const float* d1bi, const float* d1bh,
               const float* pw, const float* pb,
               float* out, char* ws, int useXs) {
  extern __shared__ char smem[];
  int tid = threadIdx.x, bid = blockIdx.x;
  int group = bid >> 6;
  int r = bid & 63;
  bool isL1 = (r >= 32);
  int hcTile = r & 31;
  int hc0 = hcTile * 16;
  int m0 = group * 64;
  unsigned* slots = (unsigned*)(ws + WS_BAR) + (size_t)group * 1024;
  int mySlot = isL1 ? 32 + hcTile : hcTile;
  char* xs = useXs ? (ws + WS_XS) : nullptr;

  _Float16* h0b[4]; _Float16* h1b[2];
  h0b[0] = (_Float16*)(ws + WS_HOFF);
  h0b[1] = (_Float16*)(ws + WS_HOFF + 1 * HBYTES);
  h0b[2] = (_Float16*)(ws + WS_HOFF + 2 * HBYTES);
  h0b[3] = (_Float16*)(ws + WS_HOFF + 3 * HBYTES);
  h1b[0] = (_Float16*)(ws + WS_HOFF + 4 * HBYTES);
  h1b[1] = (_Float16*)(ws + WS_HOFF + 5 * HBYTES);

  float creg[4];
  creg[0] = 0.f; creg[1] = 0.f; creg[2] = 0.f; creg[3] = 0.f;

  // zero the "step -1" buffers (h0[3], h1[1]) group slice
  {
    int t16 = r * 256 + tid;
    char* base = (t16 < 8192) ? (char*)h0b[3] : (char*)h1b[1];
    int idx = t16 & 8191;
    astore8z(base + (size_t)m0 * HHD * 2 + (size_t)idx * 8);
  }

  // one-time x -> xs transpose (fp32 -> fp16 swizzled), block r does t=r+64k
  if (xs) {
    int m = m0 + (tid & 63);
    int cb = (tid >> 6) * 16;
    int rt = m >> 4, l15m = m & 15;
    for (int k = 0; k < 8; ++k) {
      int t = r + k * 64;
      const float* xp = x + (size_t)m * (TINN * FF) + (size_t)t * FF + cb;
      v4f f0 = *(const v4f*)(xp);
      v4f f1 = *(const v4f*)(xp + 4);
      v4f f2 = *(const v4f*)(xp + 8);
      v4f f3 = *(const v4f*)(xp + 12);
      v4h h0_, h1_, h2_, h3_;
#pragma unroll
      for (int e = 0; e < 4; ++e) {
        h0_[e] = (_Float16)f0[e]; h1_[e] = (_Float16)f1[e];
        h2_[e] = (_Float16)f2[e]; h3_[e] = (_Float16)f3[e];
      }
      char* xt = xs + (size_t)t * XS_TBYTES;
      v4h hs[4] = {h0_, h1_, h2_, h3_};
#pragma unroll
      for (int s = 0; s < 4; ++s) {
        int c0 = cb + 4 * s;
        int off = (rt * 2 + ((c0 >> 5) & 1)) * 1024 +
                  ((c0 >> 3) & 3) * 256 + l15m * 16 + (c0 & 7) * 2;
        astore8((_Float16*)(xt + off), hs[s]);
      }
    }
  }

  if (!isL1) {
    loadWeights(tid, hc0, e0wi, 64, 64, e0wh, 576);
    if (tid < 64) {
      int n = (tid >> 4) * HHD + hc0 + (tid & 15);
      ((float*)(smem + BIAS_OFF))[tid] = e0bi[n] + e0bh[n];
    }
  } else {
    loadWeights(tid, hc0, e1wi, 512, 512, e1wh, 1024);
    if (tid < 64) {
      int n = (tid >> 4) * HHD + hc0 + (tid & 15);
      ((float*)(smem + BIAS_OFF))[tid] = e1bi[n] + e1bh[n];
    }
  }
  signalDone(slots, mySlot, 1);

  if (!isL1) {
    // ---------------- encoder layer 0 ----------------
    for (int p = 0; p < TINN; ++p)
      stepEnc0(tid, m0, hc0, slots, mySlot, p,
               xs ? xs + (size_t)p * XS_TBYTES : nullptr,
               xs ? nullptr : x + (size_t)p * FF,
               h0b[(p + 3) & 3], h0b[p & 3], creg);
    // ---------------- decoder layer 0 ----------------
    loadWeights(tid, hc0, d0wh, 512, 512, nullptr, 512);
    if (tid < 64) {
      int n = (tid >> 4) * HHD + hc0 + (tid & 15);
      ((float*)(smem + BIAS_OFF))[tid] = d0bi[n] + d0bh[n];
      ((float*)(smem + WIH0_OFF))[tid] = d0wi[n];
    }
    for (int k = tid; k < 512; k += 256) ((float*)(smem + PROJW_OFF))[k] = pw[k];
    if (tid == 0) ((float*)(smem + PROJB_OFF))[0] = pb[0];
    for (int t = 0; t <= TOUTN; ++t) {
      int u = TINN + t;
      waitRole(slots, 32, u + 1);     // h1(t-1) ready
      float* prevl = (float*)(smem + PREV_OFF);
      if (t == 0) {
        if (tid < 64)
          prevl[tid] = x[(size_t)(m0 + tid) * (TINN * FF) + 511 * 64 + 63];
      } else {
        float* part = (float*)(smem + PART_OFF);
        float* pjw = (float*)(smem + PROJW_OFF);
        const _Float16* h1base = h1b[(u + 1) & 1];
        int m = m0 + (tid >> 2);
        int rt = m >> 4, l15m = m & 15;
        int kc0 = (tid & 3) * 2;
        float s = 0.f;
#pragma unroll
        for (int kc = kc0; kc < kc0 + 2; ++kc)
#pragma unroll
          for (int ks = 0; ks < 2; ++ks)
#pragma unroll
            for (int q = 0; q < 4; ++q) {
              int off = (rt * 8 + kc) * 2048 + ks * 1024 + q * 256 + l15m * 16;
              v8h hv = aload16(h1base + off / 2);
              const float* w = pjw + kc * 64 + ks * 32 + q * 8;
#pragma unroll
              for (int e = 0; e < 8; ++e) s += (float)hv[e] * w[e];
            }
        part[tid] = s;
        __syncthreads();
        if (tid < 64) {
          float p4 = part[tid * 4] + part[tid * 4 + 1] + part[tid * 4 + 2] +
                     part[tid * 4 + 3] + ((float*)(smem + PROJB_OFF))[0];
          prevl[tid] = p4;
          if (hcTile == 0) out[(size_t)(m0 + tid) * TOUTN + (t - 1)] = p4;
        }
      }
      __syncthreads();
      if (t < TOUTN)
        stepDec0(tid, m0, hc0, slots, mySlot, u, h0b[(u + 3) & 3], h0b[u & 3], creg);
    }
  } else {
    // ---------------- encoder layer 1 ----------------
    for (int s = 0; s < TINN; ++s)
      stepL1(tid, m0, hc0, slots, mySlot, s + 1, s + 2,
             h0b[s & 3], h1b[(s + 1) & 1], h1b[s & 1], creg);
    // ---------------- decoder layer 1 ----------------
    loadWeights(tid, hc0, d1wi, 512, 512, d1wh, 1024);
    if (tid < 64) {
      int n = (tid >> 4) * HHD + hc0 + (tid & 15);
      ((float*)(smem + BIAS_OFF))[tid] = d1bi[n] + d1bh[n];
    }
    for (int t = 0; t < TOUTN; ++t) {
      int u = TINN + t;
      stepL1(tid, m0, hc0, slots, mySlot, u + 1, u + 2,
             h0b[u & 3], h1b[(u + 1) & 1], h1b[u & 1], creg);
    }
  }
}

extern "C" void kernel_launch(void* const* d_in, const int* in_sizes, int n_in,
                              void* d_out, int out_size, void* d_ws, size_t ws_size,
                              hipStream_t stream) {
  const float* x = (const float*)d_in[0];
  const float* e0wi = (const float*)d_in[2];
  const float* e0wh = (const float*)d_in[3];
  const float* e0bi = (const float*)d_in[4];
  const float* e0bh = (const float*)d_in[5];
  const float* e1wi = (const float*)d_in[6];
  const float* e1wh = (const float*)d_in[7];
  const float* e1bi = (const float*)d_in[8];
  const float* e1bh = (const float*)d_in[9];
  const float* d0wi = (const float*)d_in[10];
  const float* d0wh = (const float*)d_in[11];
  const float* d0bi = (const float*)d_in[12];
  const float* d0bh = (const float*)d_in[13];
  const float* d1wi = (const float*)d_in[14];
  const float* d1wh = (const float*)d_in[15];
  const float* d1bi = (const float*)d_in[16];
  const float* d1bh = (const float*)d_in[17];
  const float* pw = (const float*)d_in[18];
  const float* pb = (const float*)d_in[19];

  int useXs = (ws_size >= WS_NEED) ? 1 : 0;
  (void)hipFuncSetAttribute((const void*)seq2seq_kernel,
                            hipFuncAttributeMaxDynamicSharedMemorySize, SMEM_TOTAL);
  (void)hipMemsetAsync(d_ws, 0, 16384, stream);  // progress slots
  seq2seq_kernel<<<dim3(256), dim3(256), SMEM_TOTAL, stream>>>(
      x, e0wi, e0wh, e0bi, e0bh, e1wi, e1wh, e1bi, e1bh,
      d0wi, d0wh, d0bi, d0bh, d1wi, d1wh, d1bi, d1bh,
      pw, pb, (float*)d_out, (char*)d_ws, useXs);
}